// Round 2
// baseline (6108.584 us; speedup 1.0000x reference)
//
#include <hip/hip_runtime.h>
#include <hip/hip_bf16.h>

typedef __hip_bfloat16 bf16;

// Problem constants (B=256, L=64, D=1024, H=16, HD=64, HG=8, HDG=128)
#define BL    16384   // B*L rows
#define DDIM  1024
#define NREL  65      // 2*MAXREL+1

__device__ inline float toF(float x) { return x; }
__device__ inline float toF(bf16 x)  { return __bfloat162float(x); }
__device__ inline void storeT(float* p, float v) { *p = v; }
__device__ inline void storeT(bf16* p, float v)  { *p = __float2bfloat16(v); }

// ---------------------------------------------------------------------------
// GEMM: C[m,n] = (a1*A[m,:] + a2*A2[m,:]) . W[n,:] + bias[n]
// A, A2: [M,K] TA row-major; W: [N,K] fp32 row-major (torch Linear weight)
// 64x64 tile, BK=16, 256 threads, 4x4 accumulators per thread, fp32 accum.
// ---------------------------------------------------------------------------
template <typename TA, typename TC>
__global__ __launch_bounds__(256) void gemm_bias_kernel(
    const TA* __restrict__ A, const TA* __restrict__ A2,
    const float* __restrict__ W, const float* __restrict__ bias,
    TC* __restrict__ C, int M, int N, int K, float alpha1, float alpha2)
{
    __shared__ float As[64][17];   // +1 pad: kills 4-way bank conflicts
    __shared__ float Ws[64][17];
    const int t  = threadIdx.x;
    const int tx = t & 15;
    const int ty = t >> 4;
    const int rowBase = blockIdx.y << 6;
    const int colBase = blockIdx.x << 6;
    const int lr = t >> 2;         // load row 0..63
    const int lc = (t & 3) << 2;   // load col 0,4,8,12

    const TA*    Arow  = A + (size_t)(rowBase + lr) * K + lc;
    const float* Wrow  = W + (size_t)(colBase + lr) * K + lc;
    const TA*    A2row = A2 ? (A2 + (size_t)(rowBase + lr) * K + lc) : nullptr;

    float acc[4][4] = {};

    for (int k0 = 0; k0 < K; k0 += 16) {
        float f0 = alpha1 * toF(Arow[k0 + 0]);
        float f1 = alpha1 * toF(Arow[k0 + 1]);
        float f2 = alpha1 * toF(Arow[k0 + 2]);
        float f3 = alpha1 * toF(Arow[k0 + 3]);
        if (A2row) {
            f0 += alpha2 * toF(A2row[k0 + 0]);
            f1 += alpha2 * toF(A2row[k0 + 1]);
            f2 += alpha2 * toF(A2row[k0 + 2]);
            f3 += alpha2 * toF(A2row[k0 + 3]);
        }
        As[lr][lc + 0] = f0;
        As[lr][lc + 1] = f1;
        As[lr][lc + 2] = f2;
        As[lr][lc + 3] = f3;
        Ws[lr][lc + 0] = Wrow[k0 + 0];
        Ws[lr][lc + 1] = Wrow[k0 + 1];
        Ws[lr][lc + 2] = Wrow[k0 + 2];
        Ws[lr][lc + 3] = Wrow[k0 + 3];
        __syncthreads();
#pragma unroll
        for (int kk = 0; kk < 16; ++kk) {
            float a0 = As[ty * 4 + 0][kk];
            float a1 = As[ty * 4 + 1][kk];
            float a2 = As[ty * 4 + 2][kk];
            float a3 = As[ty * 4 + 3][kk];
            float w0 = Ws[tx * 4 + 0][kk];
            float w1 = Ws[tx * 4 + 1][kk];
            float w2 = Ws[tx * 4 + 2][kk];
            float w3 = Ws[tx * 4 + 3][kk];
            acc[0][0] += a0 * w0; acc[0][1] += a0 * w1; acc[0][2] += a0 * w2; acc[0][3] += a0 * w3;
            acc[1][0] += a1 * w0; acc[1][1] += a1 * w1; acc[1][2] += a1 * w2; acc[1][3] += a1 * w3;
            acc[2][0] += a2 * w0; acc[2][1] += a2 * w1; acc[2][2] += a2 * w2; acc[2][3] += a2 * w3;
            acc[3][0] += a3 * w0; acc[3][1] += a3 * w1; acc[3][2] += a3 * w2; acc[3][3] += a3 * w3;
        }
        __syncthreads();
    }
#pragma unroll
    for (int i = 0; i < 4; ++i) {
#pragma unroll
        for (int j = 0; j < 4; ++j) {
            int row = rowBase + ty * 4 + i;
            int col = colBase + tx * 4 + j;
            float v = acc[i][j] + bias[col];
            storeT(&C[(size_t)row * N + col], v);
        }
    }
}

// ---------------------------------------------------------------------------
// Local attention with relative-position bias.
// One block per (b,h). q,k,v tiles are [64, 64] of head h.
// score[l,r] = (q[l].k[r])/8 + q[l].rel_k[clip(r-l,-32,32)+32]
// ---------------------------------------------------------------------------
__global__ __launch_bounds__(256) void local_attn_kernel(
    const bf16* __restrict__ Q, const bf16* __restrict__ K,
    const bf16* __restrict__ V, const float* __restrict__ RelK,
    bf16* __restrict__ Out)
{
    __shared__ float qs[64][64];       // 16.0 KB (reads are broadcast)
    __shared__ bf16  ks[64][66];       // 8.25 KB (odd word stride -> no conflicts)
    __shared__ bf16  vs[64][66];       // 8.25 KB
    __shared__ bf16  rs[NREL][66];     // 8.4 KB
    __shared__ float sc[64][65];       // 16.25 KB   total ~57 KB < 64 KB

    const int t = threadIdx.x;
    const int b = blockIdx.x >> 4;     // H = 16
    const int h = blockIdx.x & 15;
    const size_t base = ((size_t)b * 64) * DDIM + (size_t)h * 64;

    for (int i = t; i < 64 * 64; i += 256) {
        int l = i >> 6, d = i & 63;
        size_t g = base + (size_t)l * DDIM + d;
        qs[l][d] = __bfloat162float(Q[g]);
        ks[l][d] = K[g];
        vs[l][d] = V[g];
    }
    for (int i = t; i < NREL * 64; i += 256) {
        rs[i >> 6][i & 63] = __float2bfloat16(RelK[i]);
    }
    __syncthreads();

    // scores + rel bias
    for (int i = t; i < 64 * 64; i += 256) {
        int l = i >> 6, r = i & 63;
        int rel = r - l;
        rel = rel < -32 ? -32 : (rel > 32 ? 32 : rel);
        int rid = rel + 32;
        float s1 = 0.f, s2 = 0.f;
#pragma unroll 8
        for (int d = 0; d < 64; ++d) {
            float q = qs[l][d];
            s1 += q * __bfloat162float(ks[r][d]);
            s2 += q * __bfloat162float(rs[rid][d]);
        }
        sc[l][r] = s1 * 0.125f + s2;
    }
    __syncthreads();

    // softmax over r, one thread per row
    if (t < 64) {
        float m = -1e30f;
        for (int r = 0; r < 64; ++r) m = fmaxf(m, sc[t][r]);
        float s = 0.f;
        for (int r = 0; r < 64; ++r) {
            float e = __expf(sc[t][r] - m);
            sc[t][r] = e;
            s += e;
        }
        float inv = 1.f / s;
        for (int r = 0; r < 64; ++r) sc[t][r] *= inv;
    }
    __syncthreads();

    // out = attn @ v
    for (int i = t; i < 64 * 64; i += 256) {
        int l = i >> 6, d = i & 63;
        float acc = 0.f;
#pragma unroll 8
        for (int r = 0; r < 64; ++r) acc += sc[l][r] * __bfloat162float(vs[r][d]);
        Out[base + (size_t)l * DDIM + d] = __float2bfloat16(acc);
    }
}

// ---------------------------------------------------------------------------
// Global attention (standard MHA, 8 heads, hd=128).
// One block per (b, hg, half): covers 32 q-rows, all 64 k/v rows.
// ---------------------------------------------------------------------------
__global__ __launch_bounds__(256) void global_attn_kernel(
    const bf16* __restrict__ Qg, const bf16* __restrict__ Kg,
    const bf16* __restrict__ Vg, bf16* __restrict__ Out)
{
    __shared__ bf16  qs[32][130];   // 8.125 KB
    __shared__ bf16  ks[64][130];   // 16.25 KB
    __shared__ bf16  vs[64][130];   // 16.25 KB
    __shared__ float sc[32][65];    // 8.125 KB    total ~49 KB

    const int t = threadIdx.x;
    const int blk = blockIdx.x;
    const int b    = blk >> 4;
    const int rem  = blk & 15;
    const int hg   = rem >> 1;
    const int half = rem & 1;
    const size_t colOff = (size_t)hg * 128;

    for (int i = t; i < 32 * 128; i += 256) {
        int l = i >> 7, d = i & 127;
        int row = b * 64 + half * 32 + l;
        qs[l][d] = Qg[(size_t)row * DDIM + colOff + d];
    }
    for (int i = t; i < 64 * 128; i += 256) {
        int r = i >> 7, d = i & 127;
        int row = b * 64 + r;
        ks[r][d] = Kg[(size_t)row * DDIM + colOff + d];
        vs[r][d] = Vg[(size_t)row * DDIM + colOff + d];
    }
    __syncthreads();

    for (int i = t; i < 32 * 64; i += 256) {
        int l = i >> 6, r = i & 63;
        float s = 0.f;
#pragma unroll 8
        for (int d = 0; d < 128; ++d)
            s += __bfloat162float(qs[l][d]) * __bfloat162float(ks[r][d]);
        sc[l][r] = s * 0.08838834764831845f;   // 1/sqrt(128)
    }
    __syncthreads();

    if (t < 32) {
        float m = -1e30f;
        for (int r = 0; r < 64; ++r) m = fmaxf(m, sc[t][r]);
        float s = 0.f;
        for (int r = 0; r < 64; ++r) {
            float e = __expf(sc[t][r] - m);
            sc[t][r] = e;
            s += e;
        }
        float inv = 1.f / s;
        for (int r = 0; r < 64; ++r) sc[t][r] *= inv;
    }
    __syncthreads();

    for (int i = t; i < 32 * 128; i += 256) {
        int l = i >> 7, d = i & 127;
        float acc = 0.f;
#pragma unroll 8
        for (int r = 0; r < 64; ++r) acc += sc[l][r] * __bfloat162float(vs[r][d]);
        int row = b * 64 + half * 32 + l;
        Out[(size_t)row * DDIM + colOff + d] = __float2bfloat16(acc);
    }
}

// ---------------------------------------------------------------------------
extern "C" void kernel_launch(void* const* d_in, const int* in_sizes, int n_in,
                              void* d_out, int out_size, void* d_ws, size_t ws_size,
                              hipStream_t stream)
{
    // All reference inputs are float32.
    const float* query   = (const float*)d_in[0];
    const float* key     = (const float*)d_in[1];
    const float* value   = (const float*)d_in[2];
    const float* Wq      = (const float*)d_in[3];
    const float* bq      = (const float*)d_in[4];
    const float* Wk      = (const float*)d_in[5];
    const float* bk      = (const float*)d_in[6];
    const float* Wv      = (const float*)d_in[7];
    const float* bv      = (const float*)d_in[8];
    const float* Wo      = (const float*)d_in[9];
    const float* bo      = (const float*)d_in[10];
    const float* rel_k   = (const float*)d_in[11];
    // d_in[12] = rel_v: looked up but unused by the reference
    const float* g_in_w  = (const float*)d_in[13];
    const float* g_in_b  = (const float*)d_in[14];
    const float* g_out_w = (const float*)d_in[15];
    const float* g_out_b = (const float*)d_in[16];

    // Workspace: 5 bf16 slots of BL*DDIM (32 MiB each) = 160 MiB peak.
    char* ws = (char*)d_ws;
    const size_t SZ = (size_t)BL * DDIM * sizeof(bf16);
    bf16* s0 = (bf16*)(ws + 0 * SZ);   // Qg, later Ql
    bf16* s1 = (bf16*)(ws + 1 * SZ);   // Kg, later Kl
    bf16* s2 = (bf16*)(ws + 2 * SZ);   // Vg, later Vl
    bf16* s3 = (bf16*)(ws + 3 * SZ);   // Gout, later Lout
    bf16* s4 = (bf16*)(ws + 4 * SZ);   // Gproj

    float* out = (float*)d_out;

    dim3 blk(256);
    dim3 gGemm(DDIM / 64, BL / 64);   // (16, 256)
    const float* nullA = nullptr;
    const bf16*  nullB = nullptr;

    // ---- global branch first (frees its slots for the local branch) ----
    // packed in_proj: rows [0,1024)=Q, [1024,2048)=K, [2048,3072)=V
    gemm_bias_kernel<float, bf16><<<gGemm, blk, 0, stream>>>(
        query, nullA, g_in_w, g_in_b, s0, BL, DDIM, DDIM, 1.f, 0.f);
    gemm_bias_kernel<float, bf16><<<gGemm, blk, 0, stream>>>(
        key, nullA, g_in_w + (size_t)1024 * DDIM, g_in_b + 1024, s1, BL, DDIM, DDIM, 1.f, 0.f);
    gemm_bias_kernel<float, bf16><<<gGemm, blk, 0, stream>>>(
        value, nullA, g_in_w + (size_t)2048 * DDIM, g_in_b + 2048, s2, BL, DDIM, DDIM, 1.f, 0.f);

    global_attn_kernel<<<dim3(256 * 16), blk, 0, stream>>>(s0, s1, s2, s3);

    gemm_bias_kernel<bf16, bf16><<<gGemm, blk, 0, stream>>>(
        s3, nullB, g_out_w, g_out_b, s4, BL, DDIM, DDIM, 1.f, 0.f);

    // ---- local branch (reuses s0..s3) ----
    gemm_bias_kernel<float, bf16><<<gGemm, blk, 0, stream>>>(
        query, nullA, Wq, bq, s0, BL, DDIM, DDIM, 1.f, 0.f);
    gemm_bias_kernel<float, bf16><<<gGemm, blk, 0, stream>>>(
        key, nullA, Wk, bk, s1, BL, DDIM, DDIM, 1.f, 0.f);
    gemm_bias_kernel<float, bf16><<<gGemm, blk, 0, stream>>>(
        value, nullA, Wv, bv, s2, BL, DDIM, DDIM, 1.f, 0.f);

    local_attn_kernel<<<dim3(256 * 16), blk, 0, stream>>>(s0, s1, s2, rel_k, s3);

    // ---- final: (0.7*local + 0.3*glob) @ Wo^T + bo -> fp32 out ----
    gemm_bias_kernel<bf16, float><<<gGemm, blk, 0, stream>>>(
        s3, s4, Wo, bo, out, BL, DDIM, DDIM, 0.7f, 0.3f);
}

// Round 3
// 1359.068 us; speedup vs baseline: 4.4947x; 4.4947x over previous
//
#include <hip/hip_runtime.h>
#include <hip/hip_bf16.h>

typedef __hip_bfloat16 bf16;
typedef __bf16  bf16x8 __attribute__((ext_vector_type(8)));
typedef float   f32x4  __attribute__((ext_vector_type(4)));

// Problem constants (B=256, L=64, D=1024, H=16, HD=64, HG=8, HDG=128)
#define BL    16384   // B*L rows
#define DDIM  1024
#define NREL  65      // 2*MAXREL+1

__device__ inline void storeT(float* p, float v) { *p = v; }
__device__ inline void storeT(bf16* p, float v)  { *p = __float2bfloat16(v); }

#define GLOBAL_AS(p) ((const __attribute__((address_space(1))) void*)(p))
#define LDS_AS(p)    ((__attribute__((address_space(3))) void*)(p))

// ---------------------------------------------------------------------------
// fp32 -> bf16 conversion, 4 elems/thread, vectorized
// ---------------------------------------------------------------------------
__global__ __launch_bounds__(256) void cvt_f32_bf16(const float* __restrict__ in,
                                                    bf16* __restrict__ out, int n)
{
    int i = (blockIdx.x * 256 + threadIdx.x) * 4;
    if (i >= n) return;
    float4 v = *(const float4*)(in + i);
    union { bf16 h[4]; uint2 u; } o;
    o.h[0] = __float2bfloat16(v.x);
    o.h[1] = __float2bfloat16(v.y);
    o.h[2] = __float2bfloat16(v.z);
    o.h[3] = __float2bfloat16(v.w);
    *(uint2*)(out + i) = o.u;
}

// out = 0.7*a + 0.3*b  (bf16 -> bf16)
__global__ __launch_bounds__(256) void blend_kernel(const bf16* __restrict__ a,
                                                    const bf16* __restrict__ b,
                                                    bf16* __restrict__ out, int n)
{
    int i = (blockIdx.x * 256 + threadIdx.x) * 4;
    if (i >= n) return;
    union { bf16 h[4]; uint2 u; } ua, ub, o;
    ua.u = *(const uint2*)(a + i);
    ub.u = *(const uint2*)(b + i);
#pragma unroll
    for (int k = 0; k < 4; ++k)
        o.h[k] = __float2bfloat16(0.7f * __bfloat162float(ua.h[k]) +
                                  0.3f * __bfloat162float(ub.h[k]));
    *(uint2*)(out + i) = o.u;
}

// ---------------------------------------------------------------------------
// MFMA bf16 GEMM (m97 structure): C[m,n] = A[m,:] . W[n,:] + bias[n]
// A: [M,K] bf16 row-major; W: [N,K] bf16 row-major (both K-contiguous).
// 128x128 tile, BK=64, 256 threads = 4 waves (2x2 quadrants of 64x64),
// 4x4 16x16x32 fragments per wave, global_load_lds width=16 staging.
// ---------------------------------------------------------------------------
template <typename TC>
__global__ __launch_bounds__(256) void gemm_mfma(
    const bf16* __restrict__ A, const bf16* __restrict__ W,
    const float* __restrict__ bias, TC* __restrict__ C, int M, int N, int K)
{
    __shared__ __align__(16) bf16 As[128 * 64];
    __shared__ __align__(16) bf16 Ws[128 * 64];

    const int t    = threadIdx.x;
    const int lane = t & 63;
    const int wv   = t >> 6;        // wave 0..3
    const int wr   = wv >> 1;       // quadrant row
    const int wc   = wv & 1;        // quadrant col
    const int rowBase = blockIdx.y * 128;
    const int colBase = blockIdx.x * 128;

    const int sub  = lane >> 3;       // row within 8-row staging group
    const int koff = (lane & 7) * 8;  // k-element offset within 64

    f32x4 acc[4][4] = {};

    for (int k0 = 0; k0 < K; k0 += 64) {
        // ---- stage A,W tiles: each wave 4x8 rows, 16B/lane direct-to-LDS ----
#pragma unroll
        for (int i = 0; i < 4; ++i) {
            const int rA = wv * 32 + i * 8;           // wave-uniform
            const bf16* gA = A + (size_t)(rowBase + rA + sub) * K + k0 + koff;
            __builtin_amdgcn_global_load_lds(GLOBAL_AS(gA), LDS_AS(As + rA * 64), 16, 0, 0);
            const bf16* gW = W + (size_t)(colBase + rA + sub) * K + k0 + koff;
            __builtin_amdgcn_global_load_lds(GLOBAL_AS(gW), LDS_AS(Ws + rA * 64), 16, 0, 0);
        }
        __syncthreads();

        // ---- compute: 2 k-steps of 32, 16 MFMA each ----
#pragma unroll
        for (int kk = 0; kk < 64; kk += 32) {
            bf16x8 af[4], bfr[4];
#pragma unroll
            for (int i = 0; i < 4; ++i) {
                const int rowL = wr * 64 + i * 16 + (lane & 15);
                af[i]  = *(const bf16x8*)(As + rowL * 64 + kk + (lane >> 4) * 8);
                const int colL = wc * 64 + i * 16 + (lane & 15);
                bfr[i] = *(const bf16x8*)(Ws + colL * 64 + kk + (lane >> 4) * 8);
            }
#pragma unroll
            for (int i = 0; i < 4; ++i)
#pragma unroll
                for (int j = 0; j < 4; ++j)
                    acc[i][j] = __builtin_amdgcn_mfma_f32_16x16x32_bf16(
                        af[i], bfr[j], acc[i][j], 0, 0, 0);
        }
        __syncthreads();
    }

    // ---- epilogue: C/D layout col=lane&15, row=(lane>>4)*4+reg ----
#pragma unroll
    for (int j = 0; j < 4; ++j) {
        const int col = colBase + wc * 64 + j * 16 + (lane & 15);
        const float bv = bias[col];
#pragma unroll
        for (int i = 0; i < 4; ++i) {
#pragma unroll
            for (int r = 0; r < 4; ++r) {
                const int row = rowBase + wr * 64 + i * 16 + (lane >> 4) * 4 + r;
                storeT(&C[(size_t)row * N + col], acc[i][j][r] + bv);
            }
        }
    }
}

// ---------------------------------------------------------------------------
// Local attention with relative-position bias. One block per (b,h).
// score[l,r] = (q[l].k[r])/8 + q[l].rel_k[clip(r-l,-32,32)+32]
// ---------------------------------------------------------------------------
__global__ __launch_bounds__(256) void local_attn_kernel(
    const bf16* __restrict__ Q, const bf16* __restrict__ K,
    const bf16* __restrict__ V, const float* __restrict__ RelK,
    bf16* __restrict__ Out)
{
    __shared__ float qs[64][64];
    __shared__ bf16  ks[64][66];
    __shared__ bf16  vs[64][66];
    __shared__ bf16  rs[NREL][66];
    __shared__ float sc[64][65];

    const int t = threadIdx.x;
    const int b = blockIdx.x >> 4;     // H = 16
    const int h = blockIdx.x & 15;
    const size_t base = ((size_t)b * 64) * DDIM + (size_t)h * 64;

    for (int i = t; i < 64 * 64; i += 256) {
        int l = i >> 6, d = i & 63;
        size_t g = base + (size_t)l * DDIM + d;
        qs[l][d] = __bfloat162float(Q[g]);
        ks[l][d] = K[g];
        vs[l][d] = V[g];
    }
    for (int i = t; i < NREL * 64; i += 256)
        rs[i >> 6][i & 63] = __float2bfloat16(RelK[i]);
    __syncthreads();

    for (int i = t; i < 64 * 64; i += 256) {
        int l = i >> 6, r = i & 63;
        int rel = r - l;
        rel = rel < -32 ? -32 : (rel > 32 ? 32 : rel);
        int rid = rel + 32;
        float s1 = 0.f, s2 = 0.f;
#pragma unroll 8
        for (int d = 0; d < 64; ++d) {
            float q = qs[l][d];
            s1 += q * __bfloat162float(ks[r][d]);
            s2 += q * __bfloat162float(rs[rid][d]);
        }
        sc[l][r] = s1 * 0.125f + s2;
    }
    __syncthreads();

    if (t < 64) {
        float m = -1e30f;
        for (int r = 0; r < 64; ++r) m = fmaxf(m, sc[t][r]);
        float s = 0.f;
        for (int r = 0; r < 64; ++r) {
            float e = __expf(sc[t][r] - m);
            sc[t][r] = e;
            s += e;
        }
        float inv = 1.f / s;
        for (int r = 0; r < 64; ++r) sc[t][r] *= inv;
    }
    __syncthreads();

    for (int i = t; i < 64 * 64; i += 256) {
        int l = i >> 6, d = i & 63;
        float acc = 0.f;
#pragma unroll 8
        for (int r = 0; r < 64; ++r) acc += sc[l][r] * __bfloat162float(vs[r][d]);
        Out[base + (size_t)l * DDIM + d] = __float2bfloat16(acc);
    }
}

// ---------------------------------------------------------------------------
// Global attention (standard MHA, 8 heads, hd=128). One block per (b,hg,half).
// ---------------------------------------------------------------------------
__global__ __launch_bounds__(256) void global_attn_kernel(
    const bf16* __restrict__ Qg, const bf16* __restrict__ Kg,
    const bf16* __restrict__ Vg, bf16* __restrict__ Out)
{
    __shared__ bf16  qs[32][130];
    __shared__ bf16  ks[64][130];
    __shared__ bf16  vs[64][130];
    __shared__ float sc[32][65];

    const int t = threadIdx.x;
    const int blk = blockIdx.x;
    const int b    = blk >> 4;
    const int rem  = blk & 15;
    const int hg   = rem >> 1;
    const int half = rem & 1;
    const size_t colOff = (size_t)hg * 128;

    for (int i = t; i < 32 * 128; i += 256) {
        int l = i >> 7, d = i & 127;
        int row = b * 64 + half * 32 + l;
        qs[l][d] = Qg[(size_t)row * DDIM + colOff + d];
    }
    for (int i = t; i < 64 * 128; i += 256) {
        int r = i >> 7, d = i & 127;
        int row = b * 64 + r;
        ks[r][d] = Kg[(size_t)row * DDIM + colOff + d];
        vs[r][d] = Vg[(size_t)row * DDIM + colOff + d];
    }
    __syncthreads();

    for (int i = t; i < 32 * 64; i += 256) {
        int l = i >> 6, r = i & 63;
        float s = 0.f;
#pragma unroll 8
        for (int d = 0; d < 128; ++d)
            s += __bfloat162float(qs[l][d]) * __bfloat162float(ks[r][d]);
        sc[l][r] = s * 0.08838834764831845f;   // 1/sqrt(128)
    }
    __syncthreads();

    if (t < 32) {
        float m = -1e30f;
        for (int r = 0; r < 64; ++r) m = fmaxf(m, sc[t][r]);
        float s = 0.f;
        for (int r = 0; r < 64; ++r) {
            float e = __expf(sc[t][r] - m);
            sc[t][r] = e;
            s += e;
        }
        float inv = 1.f / s;
        for (int r = 0; r < 64; ++r) sc[t][r] *= inv;
    }
    __syncthreads();

    for (int i = t; i < 32 * 128; i += 256) {
        int l = i >> 7, d = i & 127;
        float acc = 0.f;
#pragma unroll 8
        for (int r = 0; r < 64; ++r) acc += sc[l][r] * __bfloat162float(vs[r][d]);
        int row = b * 64 + half * 32 + l;
        Out[(size_t)row * DDIM + colOff + d] = __float2bfloat16(acc);
    }
}

// ---------------------------------------------------------------------------
extern "C" void kernel_launch(void* const* d_in, const int* in_sizes, int n_in,
                              void* d_out, int out_size, void* d_ws, size_t ws_size,
                              hipStream_t stream)
{
    // All reference inputs are float32.
    const float* query   = (const float*)d_in[0];
    const float* key     = (const float*)d_in[1];
    const float* value   = (const float*)d_in[2];
    const float* Wq      = (const float*)d_in[3];
    const float* bq      = (const float*)d_in[4];
    const float* Wk      = (const float*)d_in[5];
    const float* bk      = (const float*)d_in[6];
    const float* Wv      = (const float*)d_in[7];
    const float* bv      = (const float*)d_in[8];
    const float* Wo      = (const float*)d_in[9];
    const float* bo      = (const float*)d_in[10];
    const float* rel_k   = (const float*)d_in[11];
    // d_in[12] = rel_v: looked up but unused by the reference
    const float* g_in_w  = (const float*)d_in[13];
    const float* g_in_b  = (const float*)d_in[14];
    const float* g_out_w = (const float*)d_in[15];
    const float* g_out_b = (const float*)d_in[16];

    // Workspace: 5 activation slots (32 MiB each) + 16 MiB bf16 weights = 176 MiB
    char* ws = (char*)d_ws;
    const size_t SZ = (size_t)BL * DDIM * sizeof(bf16);
    bf16* s0 = (bf16*)(ws + 0 * SZ);
    bf16* s1 = (bf16*)(ws + 1 * SZ);
    bf16* s2 = (bf16*)(ws + 2 * SZ);
    bf16* s3 = (bf16*)(ws + 3 * SZ);
    bf16* s4 = (bf16*)(ws + 4 * SZ);
    bf16* wb = (bf16*)(ws + 5 * SZ);
    const size_t MM = (size_t)DDIM * DDIM;   // 1M elements
    bf16* wgq = wb;                // g_in rows [0,1024)
    bf16* wgk = wb + 1 * MM;       // g_in rows [1024,2048)
    bf16* wgv = wb + 2 * MM;       // g_in rows [2048,3072)
    bf16* wq  = wb + 3 * MM;
    bf16* wk  = wb + 4 * MM;
    bf16* wvw = wb + 5 * MM;
    bf16* wo  = wb + 6 * MM;
    bf16* wgo = wb + 7 * MM;

    float* out = (float*)d_out;

    dim3 blk(256);
    dim3 gGemm(DDIM / 128, BL / 128);              // (8, 128)
    const int nAct = BL * DDIM;                    // 16.7M
    dim3 gCvtA(nAct / 1024);
    dim3 gCvtW((int)MM / 1024);
    dim3 gCvtG(3 * (int)MM / 1024);

    // ---- weight conversions (fp32 -> bf16) ----
    cvt_f32_bf16<<<gCvtG, blk, 0, stream>>>(g_in_w, wgq, 3 * (int)MM);  // covers wgq/wgk/wgv
    cvt_f32_bf16<<<gCvtW, blk, 0, stream>>>(Wq, wq, (int)MM);
    cvt_f32_bf16<<<gCvtW, blk, 0, stream>>>(Wk, wk, (int)MM);
    cvt_f32_bf16<<<gCvtW, blk, 0, stream>>>(Wv, wvw, (int)MM);
    cvt_f32_bf16<<<gCvtW, blk, 0, stream>>>(Wo, wo, (int)MM);
    cvt_f32_bf16<<<gCvtW, blk, 0, stream>>>(g_out_w, wgo, (int)MM);

    // ---- global branch ----
    cvt_f32_bf16<<<gCvtA, blk, 0, stream>>>(query, s0, nAct);
    gemm_mfma<bf16><<<gGemm, blk, 0, stream>>>(s0, wgq, g_in_b, s1, BL, DDIM, DDIM);
    cvt_f32_bf16<<<gCvtA, blk, 0, stream>>>(key, s0, nAct);
    gemm_mfma<bf16><<<gGemm, blk, 0, stream>>>(s0, wgk, g_in_b + 1024, s2, BL, DDIM, DDIM);
    cvt_f32_bf16<<<gCvtA, blk, 0, stream>>>(value, s0, nAct);
    gemm_mfma<bf16><<<gGemm, blk, 0, stream>>>(s0, wgv, g_in_b + 2048, s3, BL, DDIM, DDIM);

    global_attn_kernel<<<dim3(256 * 16), blk, 0, stream>>>(s1, s2, s3, s4);
    gemm_mfma<bf16><<<gGemm, blk, 0, stream>>>(s4, wgo, g_out_b, s1, BL, DDIM, DDIM); // Gproj->s1

    // ---- local branch ----
    cvt_f32_bf16<<<gCvtA, blk, 0, stream>>>(query, s0, nAct);
    gemm_mfma<bf16><<<gGemm, blk, 0, stream>>>(s0, wq, bq, s2, BL, DDIM, DDIM);       // Ql->s2
    cvt_f32_bf16<<<gCvtA, blk, 0, stream>>>(key, s0, nAct);
    gemm_mfma<bf16><<<gGemm, blk, 0, stream>>>(s0, wk, bk, s3, BL, DDIM, DDIM);       // Kl->s3
    cvt_f32_bf16<<<gCvtA, blk, 0, stream>>>(value, s0, nAct);
    gemm_mfma<bf16><<<gGemm, blk, 0, stream>>>(s0, wvw, bv, s4, BL, DDIM, DDIM);      // Vl->s4

    local_attn_kernel<<<dim3(256 * 16), blk, 0, stream>>>(s2, s3, s4, rel_k, s0);     // Lout->s0

    // ---- blend + final projection ----
    blend_kernel<<<gCvtA, blk, 0, stream>>>(s0, s1, s2, nAct);                        // s2 = 0.7L+0.3G
    gemm_mfma<float><<<gGemm, blk, 0, stream>>>(s2, wo, bo, out, BL, DDIM, DDIM);
}

// Round 4
// 856.710 us; speedup vs baseline: 7.1303x; 1.5864x over previous
//
#include <hip/hip_runtime.h>
#include <hip/hip_bf16.h>

typedef __hip_bfloat16 bf16;
typedef __bf16  bf16x8 __attribute__((ext_vector_type(8)));
typedef float   f32x4  __attribute__((ext_vector_type(4)));

// Problem constants (B=256, L=64, D=1024, H=16, HD=64, HG=8, HDG=128)
#define BL    16384   // B*L rows
#define DDIM  1024
#define NREL  65      // 2*MAXREL+1

__device__ inline void storeT(float* p, float v) { *p = v; }
__device__ inline void storeT(bf16* p, float v)  { *p = __float2bfloat16(v); }

#define GLOBAL_AS(p) ((const __attribute__((address_space(1))) void*)(p))
#define LDS_AS(p)    ((__attribute__((address_space(3))) void*)(p))

#define MFMA16(a, b, c) __builtin_amdgcn_mfma_f32_16x16x32_bf16((a), (b), (c), 0, 0, 0)

// ---------------------------------------------------------------------------
// fp32 -> bf16 conversion, 4 elems/thread, vectorized
// ---------------------------------------------------------------------------
__global__ __launch_bounds__(256) void cvt_f32_bf16(const float* __restrict__ in,
                                                    bf16* __restrict__ out, int n)
{
    int i = (blockIdx.x * 256 + threadIdx.x) * 4;
    if (i >= n) return;
    float4 v = *(const float4*)(in + i);
    union { bf16 h[4]; uint2 u; } o;
    o.h[0] = __float2bfloat16(v.x);
    o.h[1] = __float2bfloat16(v.y);
    o.h[2] = __float2bfloat16(v.z);
    o.h[3] = __float2bfloat16(v.w);
    *(uint2*)(out + i) = o.u;
}

// out = 0.7*a + 0.3*b  (bf16 -> bf16)
__global__ __launch_bounds__(256) void blend_kernel(const bf16* __restrict__ a,
                                                    const bf16* __restrict__ b,
                                                    bf16* __restrict__ out, int n)
{
    int i = (blockIdx.x * 256 + threadIdx.x) * 4;
    if (i >= n) return;
    union { bf16 h[4]; uint2 u; } ua, ub, o;
    ua.u = *(const uint2*)(a + i);
    ub.u = *(const uint2*)(b + i);
#pragma unroll
    for (int k = 0; k < 4; ++k)
        o.h[k] = __float2bfloat16(0.7f * __bfloat162float(ua.h[k]) +
                                  0.3f * __bfloat162float(ub.h[k]));
    *(uint2*)(out + i) = o.u;
}

// ---------------------------------------------------------------------------
// MFMA bf16 GEMM (m97 structure): C[m,n] = A[m,:] . W[n,:] + bias[n]
// ---------------------------------------------------------------------------
template <typename TC>
__global__ __launch_bounds__(256) void gemm_mfma(
    const bf16* __restrict__ A, const bf16* __restrict__ W,
    const float* __restrict__ bias, TC* __restrict__ C, int M, int N, int K)
{
    __shared__ __align__(16) bf16 As[128 * 64];
    __shared__ __align__(16) bf16 Ws[128 * 64];

    const int t    = threadIdx.x;
    const int lane = t & 63;
    const int wv   = t >> 6;
    const int wr   = wv >> 1;
    const int wc   = wv & 1;
    const int rowBase = blockIdx.y * 128;
    const int colBase = blockIdx.x * 128;

    const int sub  = lane >> 3;
    const int koff = (lane & 7) * 8;

    f32x4 acc[4][4] = {};

    for (int k0 = 0; k0 < K; k0 += 64) {
#pragma unroll
        for (int i = 0; i < 4; ++i) {
            const int rA = wv * 32 + i * 8;
            const bf16* gA = A + (size_t)(rowBase + rA + sub) * K + k0 + koff;
            __builtin_amdgcn_global_load_lds(GLOBAL_AS(gA), LDS_AS(As + rA * 64), 16, 0, 0);
            const bf16* gW = W + (size_t)(colBase + rA + sub) * K + k0 + koff;
            __builtin_amdgcn_global_load_lds(GLOBAL_AS(gW), LDS_AS(Ws + rA * 64), 16, 0, 0);
        }
        __syncthreads();

#pragma unroll
        for (int kk = 0; kk < 64; kk += 32) {
            bf16x8 af[4], bfr[4];
#pragma unroll
            for (int i = 0; i < 4; ++i) {
                const int rowL = wr * 64 + i * 16 + (lane & 15);
                af[i]  = *(const bf16x8*)(As + rowL * 64 + kk + (lane >> 4) * 8);
                const int colL = wc * 64 + i * 16 + (lane & 15);
                bfr[i] = *(const bf16x8*)(Ws + colL * 64 + kk + (lane >> 4) * 8);
            }
#pragma unroll
            for (int i = 0; i < 4; ++i)
#pragma unroll
                for (int j = 0; j < 4; ++j)
                    acc[i][j] = MFMA16(af[i], bfr[j], acc[i][j]);
        }
        __syncthreads();
    }

#pragma unroll
    for (int j = 0; j < 4; ++j) {
        const int col = colBase + wc * 64 + j * 16 + (lane & 15);
        const float bv = bias[col];
#pragma unroll
        for (int i = 0; i < 4; ++i) {
#pragma unroll
            for (int r = 0; r < 4; ++r) {
                const int row = rowBase + wr * 64 + i * 16 + (lane >> 4) * 4 + r;
                storeT(&C[(size_t)row * N + col], acc[i][j][r] + bv);
            }
        }
    }
}

// ---------------------------------------------------------------------------
// MFMA local attention with relative-position bias. One block per (b,h).
// S = Q.K^T/8 + gather(Q.rel^T);  softmax in registers;  O = P.V
// ---------------------------------------------------------------------------
__global__ __launch_bounds__(256) void local_attn_mfma(
    const bf16* __restrict__ Q, const bf16* __restrict__ K,
    const bf16* __restrict__ V, const float* __restrict__ RelK,
    bf16* __restrict__ Out)
{
    __shared__ __align__(16) bf16 qs[64 * 64];    // A-operand
    __shared__ __align__(16) bf16 ks[64 * 64];    // B-operand
    __shared__ __align__(16) bf16 rs[80 * 64];    // B-operand (rows 65..79 junk, never read back)
    __shared__ __align__(16) bf16 vt[64 * 66];    // V transposed [d][r], stride 66
    __shared__ __align__(16) bf16 qrl[64 * 80];   // Q.rel^T result
    __shared__ __align__(16) bf16 ps[64 * 64];    // softmaxed P

    const int t    = threadIdx.x;
    const int lane = t & 63;
    const int wv   = t >> 6;
    const int m    = lane & 15;
    const int g4   = lane >> 4;
    const int b    = blockIdx.x >> 4;
    const int h    = blockIdx.x & 15;
    const size_t base = (size_t)b * 64 * DDIM + (size_t)h * 64;

    for (int i = t; i < 1024; i += 256) {
        int e = i * 4, l = e >> 6, d = e & 63;
        const size_t g = base + (size_t)l * DDIM + d;
        *(uint2*)(qs + l * 64 + d) = *(const uint2*)(Q + g);
        *(uint2*)(ks + l * 64 + d) = *(const uint2*)(K + g);
        const bf16* vp = V + g;
        vt[(d + 0) * 66 + l] = vp[0];
        vt[(d + 1) * 66 + l] = vp[1];
        vt[(d + 2) * 66 + l] = vp[2];
        vt[(d + 3) * 66 + l] = vp[3];
    }
    for (int i = t; i < NREL * 64; i += 256)
        rs[i] = __float2bfloat16(RelK[i]);
    __syncthreads();

    // ---- QK^T and Q.rel^T (wave wv owns score rows [wv*16, wv*16+16)) ----
    bf16x8 af[2];
    af[0] = *(const bf16x8*)(qs + (wv * 16 + m) * 64 + 0  + g4 * 8);
    af[1] = *(const bf16x8*)(qs + (wv * 16 + m) * 64 + 32 + g4 * 8);
    f32x4 accS[4] = {}, accR[5] = {};
#pragma unroll
    for (int j = 0; j < 4; ++j)
#pragma unroll
        for (int kc = 0; kc < 2; ++kc) {
            bf16x8 bk = *(const bf16x8*)(ks + (j * 16 + m) * 64 + kc * 32 + g4 * 8);
            accS[j] = MFMA16(af[kc], bk, accS[j]);
        }
#pragma unroll
    for (int p = 0; p < 5; ++p)
#pragma unroll
        for (int kc = 0; kc < 2; ++kc) {
            bf16x8 br = *(const bf16x8*)(rs + (p * 16 + m) * 64 + kc * 32 + g4 * 8);
            accR[p] = MFMA16(af[kc], br, accR[p]);
        }
    // QR -> LDS (C-layout: row = wv*16+g4*4+r, col = p*16+m); cols>64 junk, unread
#pragma unroll
    for (int p = 0; p < 5; ++p)
#pragma unroll
        for (int r = 0; r < 4; ++r)
            qrl[(wv * 16 + g4 * 4 + r) * 80 + p * 16 + m] = __float2bfloat16(accR[p][r]);
    __syncthreads();

    // ---- scores + register softmax ----
    float sc[4][4];
#pragma unroll
    for (int j = 0; j < 4; ++j) {
        const int c = j * 16 + m;
#pragma unroll
        for (int r = 0; r < 4; ++r) {
            const int l = wv * 16 + g4 * 4 + r;
            int rel = c - l;
            rel = rel < -32 ? -32 : (rel > 32 ? 32 : rel);
            sc[j][r] = accS[j][r] * 0.125f +
                       __bfloat162float(qrl[l * 80 + rel + 32]);
        }
    }
#pragma unroll
    for (int r = 0; r < 4; ++r) {
        float mx = fmaxf(fmaxf(sc[0][r], sc[1][r]), fmaxf(sc[2][r], sc[3][r]));
        mx = fmaxf(mx, __shfl_xor(mx, 1));
        mx = fmaxf(mx, __shfl_xor(mx, 2));
        mx = fmaxf(mx, __shfl_xor(mx, 4));
        mx = fmaxf(mx, __shfl_xor(mx, 8));
        float s = 0.f;
#pragma unroll
        for (int j = 0; j < 4; ++j) { float e = __expf(sc[j][r] - mx); sc[j][r] = e; s += e; }
        s += __shfl_xor(s, 1); s += __shfl_xor(s, 2);
        s += __shfl_xor(s, 4); s += __shfl_xor(s, 8);
        const float inv = 1.f / s;
#pragma unroll
        for (int j = 0; j < 4; ++j)
            ps[(wv * 16 + g4 * 4 + r) * 64 + j * 16 + m] = __float2bfloat16(sc[j][r] * inv);
    }
    __syncthreads();

    // ---- O = P.V (B-operand = V^T, stride 66, assembled from b32 reads) ----
    bf16x8 pf[2];
    pf[0] = *(const bf16x8*)(ps + (wv * 16 + m) * 64 + 0  + g4 * 8);
    pf[1] = *(const bf16x8*)(ps + (wv * 16 + m) * 64 + 32 + g4 * 8);
    f32x4 accO[4] = {};
#pragma unroll
    for (int j = 0; j < 4; ++j)
#pragma unroll
        for (int kc = 0; kc < 2; ++kc) {
            union { bf16x8 v; unsigned short u[8]; } bu;
            const unsigned short* vp =
                (const unsigned short*)vt + (j * 16 + m) * 66 + kc * 32 + g4 * 8;
#pragma unroll
            for (int c = 0; c < 8; ++c) bu.u[c] = vp[c];
            accO[j] = MFMA16(pf[kc], bu.v, accO[j]);
        }
#pragma unroll
    for (int j = 0; j < 4; ++j)
#pragma unroll
        for (int r = 0; r < 4; ++r)
            Out[base + (size_t)(wv * 16 + g4 * 4 + r) * DDIM + j * 16 + m] =
                __float2bfloat16(accO[j][r]);
}

// ---------------------------------------------------------------------------
// MFMA global attention (8 heads, hd=128). One block per (b,hg), 64 q-rows.
// NOTE: Out may alias Qg (in-place) -> no __restrict__ on those two.
// ---------------------------------------------------------------------------
__global__ __launch_bounds__(256) void global_attn_mfma(
    const bf16* Qg, const bf16* __restrict__ Kg,
    const bf16* __restrict__ Vg, bf16* Out)
{
    __shared__ __align__(16) bf16 qs[64 * 136];
    __shared__ __align__(16) bf16 ks[64 * 136];
    __shared__ __align__(16) bf16 vt[128 * 66];
    __shared__ __align__(16) bf16 ps[64 * 64];

    const int t    = threadIdx.x;
    const int lane = t & 63;
    const int wv   = t >> 6;
    const int m    = lane & 15;
    const int g4   = lane >> 4;
    const int b    = blockIdx.x >> 3;
    const int hg   = blockIdx.x & 7;
    const size_t base = (size_t)b * 64 * DDIM + (size_t)hg * 128;

    for (int i = t; i < 2048; i += 256) {
        int e = i * 4, l = e >> 7, d = e & 127;
        const size_t g = base + (size_t)l * DDIM + d;
        *(uint2*)(qs + l * 136 + d) = *(const uint2*)(Qg + g);
        *(uint2*)(ks + l * 136 + d) = *(const uint2*)(Kg + g);
        const bf16* vp = Vg + g;
        vt[(d + 0) * 66 + l] = vp[0];
        vt[(d + 1) * 66 + l] = vp[1];
        vt[(d + 2) * 66 + l] = vp[2];
        vt[(d + 3) * 66 + l] = vp[3];
    }
    __syncthreads();

    // ---- S = Q.K^T (K=128) ----
    bf16x8 af[4];
#pragma unroll
    for (int kc = 0; kc < 4; ++kc)
        af[kc] = *(const bf16x8*)(qs + (wv * 16 + m) * 136 + kc * 32 + g4 * 8);
    f32x4 accS[4] = {};
#pragma unroll
    for (int j = 0; j < 4; ++j)
#pragma unroll
        for (int kc = 0; kc < 4; ++kc) {
            bf16x8 bk = *(const bf16x8*)(ks + (j * 16 + m) * 136 + kc * 32 + g4 * 8);
            accS[j] = MFMA16(af[kc], bk, accS[j]);
        }

    // ---- register softmax ----
    float sc[4][4];
#pragma unroll
    for (int j = 0; j < 4; ++j)
#pragma unroll
        for (int r = 0; r < 4; ++r)
            sc[j][r] = accS[j][r] * 0.08838834764831845f;
#pragma unroll
    for (int r = 0; r < 4; ++r) {
        float mx = fmaxf(fmaxf(sc[0][r], sc[1][r]), fmaxf(sc[2][r], sc[3][r]));
        mx = fmaxf(mx, __shfl_xor(mx, 1));
        mx = fmaxf(mx, __shfl_xor(mx, 2));
        mx = fmaxf(mx, __shfl_xor(mx, 4));
        mx = fmaxf(mx, __shfl_xor(mx, 8));
        float s = 0.f;
#pragma unroll
        for (int j = 0; j < 4; ++j) { float e = __expf(sc[j][r] - mx); sc[j][r] = e; s += e; }
        s += __shfl_xor(s, 1); s += __shfl_xor(s, 2);
        s += __shfl_xor(s, 4); s += __shfl_xor(s, 8);
        const float inv = 1.f / s;
#pragma unroll
        for (int j = 0; j < 4; ++j)
            ps[(wv * 16 + g4 * 4 + r) * 64 + j * 16 + m] = __float2bfloat16(sc[j][r] * inv);
    }
    __syncthreads();

    // ---- O = P.V (out cols = 128) ----
    bf16x8 pf[2];
    pf[0] = *(const bf16x8*)(ps + (wv * 16 + m) * 64 + 0  + g4 * 8);
    pf[1] = *(const bf16x8*)(ps + (wv * 16 + m) * 64 + 32 + g4 * 8);
    f32x4 accO[8] = {};
#pragma unroll
    for (int j = 0; j < 8; ++j)
#pragma unroll
        for (int kc = 0; kc < 2; ++kc) {
            union { bf16x8 v; unsigned short u[8]; } bu;
            const unsigned short* vp =
                (const unsigned short*)vt + (j * 16 + m) * 66 + kc * 32 + g4 * 8;
#pragma unroll
            for (int c = 0; c < 8; ++c) bu.u[c] = vp[c];
            accO[j] = MFMA16(pf[kc], bu.v, accO[j]);
        }
#pragma unroll
    for (int j = 0; j < 8; ++j)
#pragma unroll
        for (int r = 0; r < 4; ++r)
            Out[base + (size_t)(wv * 16 + g4 * 4 + r) * DDIM + j * 16 + m] =
                __float2bfloat16(accO[j][r]);
}

// ---------------------------------------------------------------------------
extern "C" void kernel_launch(void* const* d_in, const int* in_sizes, int n_in,
                              void* d_out, int out_size, void* d_ws, size_t ws_size,
                              hipStream_t stream)
{
    const float* query   = (const float*)d_in[0];
    const float* key     = (const float*)d_in[1];
    const float* value   = (const float*)d_in[2];
    const float* Wq      = (const float*)d_in[3];
    const float* bq      = (const float*)d_in[4];
    const float* Wk      = (const float*)d_in[5];
    const float* bk      = (const float*)d_in[6];
    const float* Wv      = (const float*)d_in[7];
    const float* bv      = (const float*)d_in[8];
    const float* Wo      = (const float*)d_in[9];
    const float* bo      = (const float*)d_in[10];
    const float* rel_k   = (const float*)d_in[11];
    // d_in[12] = rel_v: unused by the reference
    const float* g_in_w  = (const float*)d_in[13];
    const float* g_in_b  = (const float*)d_in[14];
    const float* g_out_w = (const float*)d_in[15];
    const float* g_out_b = (const float*)d_in[16];

    char* ws = (char*)d_ws;
    const size_t SZ = (size_t)BL * DDIM * sizeof(bf16);   // 32 MiB
    const size_t MM = (size_t)DDIM * DDIM;
    const size_t WB = 8 * MM * sizeof(bf16);              // 16 MiB
    const bool big = ws_size >= 6 * SZ + WB;              // 208 MiB schedule?
    const int nslots = big ? 6 : 5;

    bf16* s0 = (bf16*)(ws + 0 * SZ);
    bf16* s1 = (bf16*)(ws + 1 * SZ);
    bf16* s2 = (bf16*)(ws + 2 * SZ);
    bf16* s3 = (bf16*)(ws + 3 * SZ);
    bf16* s4 = (bf16*)(ws + 4 * SZ);
    bf16* s5 = (bf16*)(ws + 5 * SZ);   // only used when big
    bf16* wb = (bf16*)(ws + nslots * SZ);
    bf16* wgq = wb;
    bf16* wgk = wb + 1 * MM;
    bf16* wgv = wb + 2 * MM;
    bf16* wq  = wb + 3 * MM;
    bf16* wk  = wb + 4 * MM;
    bf16* wvw = wb + 5 * MM;
    bf16* wo  = wb + 6 * MM;
    bf16* wgo = wb + 7 * MM;

    float* out = (float*)d_out;

    dim3 blk(256);
    dim3 gGemm(DDIM / 128, BL / 128);
    const int nAct = BL * DDIM;
    dim3 gCvtA(nAct / 1024);
    dim3 gCvtW((int)MM / 1024);
    dim3 gCvtG(3 * (int)MM / 1024);
    dim3 gLocal(256 * 16);
    dim3 gGlobal(256 * 8);

    // weight conversions
    cvt_f32_bf16<<<gCvtG, blk, 0, stream>>>(g_in_w, wgq, 3 * (int)MM);
    cvt_f32_bf16<<<gCvtW, blk, 0, stream>>>(Wq, wq, (int)MM);
    cvt_f32_bf16<<<gCvtW, blk, 0, stream>>>(Wk, wk, (int)MM);
    cvt_f32_bf16<<<gCvtW, blk, 0, stream>>>(Wv, wvw, (int)MM);
    cvt_f32_bf16<<<gCvtW, blk, 0, stream>>>(Wo, wo, (int)MM);
    cvt_f32_bf16<<<gCvtW, blk, 0, stream>>>(g_out_w, wgo, (int)MM);

    if (big) {
        // 6-slot schedule: q/k/v converted once
        cvt_f32_bf16<<<gCvtA, blk, 0, stream>>>(query, s0, nAct);
        cvt_f32_bf16<<<gCvtA, blk, 0, stream>>>(key,   s1, nAct);
        cvt_f32_bf16<<<gCvtA, blk, 0, stream>>>(value, s2, nAct);

        gemm_mfma<bf16><<<gGemm, blk, 0, stream>>>(s0, wgq, g_in_b,        s3, BL, DDIM, DDIM);
        gemm_mfma<bf16><<<gGemm, blk, 0, stream>>>(s1, wgk, g_in_b + 1024, s4, BL, DDIM, DDIM);
        gemm_mfma<bf16><<<gGemm, blk, 0, stream>>>(s2, wgv, g_in_b + 2048, s5, BL, DDIM, DDIM);
        global_attn_mfma<<<gGlobal, blk, 0, stream>>>(s3, s4, s5, s3);          // in-place
        gemm_mfma<bf16><<<gGemm, blk, 0, stream>>>(s3, wgo, g_out_b, s4, BL, DDIM, DDIM); // Gproj

        gemm_mfma<bf16><<<gGemm, blk, 0, stream>>>(s0, wq, bq, s3, BL, DDIM, DDIM);  // Ql
        gemm_mfma<bf16><<<gGemm, blk, 0, stream>>>(s1, wk, bk, s5, BL, DDIM, DDIM);  // Kl
        gemm_mfma<bf16><<<gGemm, blk, 0, stream>>>(s2, wvw, bv, s1, BL, DDIM, DDIM); // Vl
        local_attn_mfma<<<gLocal, blk, 0, stream>>>(s3, s5, s1, rel_k, s2);          // Lout

        blend_kernel<<<gCvtA, blk, 0, stream>>>(s2, s4, s0, nAct);
        gemm_mfma<float><<<gGemm, blk, 0, stream>>>(s0, wo, bo, out, BL, DDIM, DDIM);
    } else {
        // 5-slot fallback (R2-proven, 176 MiB)
        cvt_f32_bf16<<<gCvtA, blk, 0, stream>>>(query, s0, nAct);
        gemm_mfma<bf16><<<gGemm, blk, 0, stream>>>(s0, wgq, g_in_b, s1, BL, DDIM, DDIM);
        cvt_f32_bf16<<<gCvtA, blk, 0, stream>>>(key, s0, nAct);
        gemm_mfma<bf16><<<gGemm, blk, 0, stream>>>(s0, wgk, g_in_b + 1024, s2, BL, DDIM, DDIM);
        cvt_f32_bf16<<<gCvtA, blk, 0, stream>>>(value, s0, nAct);
        gemm_mfma<bf16><<<gGemm, blk, 0, stream>>>(s0, wgv, g_in_b + 2048, s3, BL, DDIM, DDIM);

        global_attn_mfma<<<gGlobal, blk, 0, stream>>>(s1, s2, s3, s4);
        gemm_mfma<bf16><<<gGemm, blk, 0, stream>>>(s4, wgo, g_out_b, s1, BL, DDIM, DDIM);

        cvt_f32_bf16<<<gCvtA, blk, 0, stream>>>(query, s0, nAct);
        gemm_mfma<bf16><<<gGemm, blk, 0, stream>>>(s0, wq, bq, s2, BL, DDIM, DDIM);
        cvt_f32_bf16<<<gCvtA, blk, 0, stream>>>(key, s0, nAct);
        gemm_mfma<bf16><<<gGemm, blk, 0, stream>>>(s0, wk, bk, s3, BL, DDIM, DDIM);
        cvt_f32_bf16<<<gCvtA, blk, 0, stream>>>(value, s0, nAct);
        gemm_mfma<bf16><<<gGemm, blk, 0, stream>>>(s0, wvw, bv, s4, BL, DDIM, DDIM);

        local_attn_mfma<<<gLocal, blk, 0, stream>>>(s2, s3, s4, rel_k, s0);

        blend_kernel<<<gCvtA, blk, 0, stream>>>(s0, s1, s2, nAct);
        gemm_mfma<float><<<gGemm, blk, 0, stream>>>(s2, wo, bo, out, BL, DDIM, DDIM);
    }
}